// Round 1
// baseline (1506.818 us; speedup 1.0000x reference)
//
#include <hip/hip_runtime.h>
#include <cstdint>
#include <cstddef>

#define L_SEQ 1024
#define BATCH 8
#define DMODEL 1024
#define DINNER 2048
#define NSTATE 16
#define DTRANK 64
#define NQ 4000
#define NROWS (BATCH * L_SEQ)   // 8192

typedef float f32x4 __attribute__((ext_vector_type(4)));
typedef __bf16 bf16x8 __attribute__((ext_vector_type(8)));

__device__ __forceinline__ unsigned short f2bf(float f) {
  union { float f; unsigned int u; } c; c.f = f;
  unsigned int u = c.u;
  unsigned int r = u + 0x7fffu + ((u >> 16) & 1u);
  return (unsigned short)(r >> 16);
}

__device__ __forceinline__ float sigmoidf_(float x) { return 1.f / (1.f + expf(-x)); }

// ---------------- weight fp32 -> bf16 cast ----------------
__global__ void cast_bf16_k(const float* __restrict__ src, unsigned short* __restrict__ dst, int n) {
  int i = blockIdx.x * blockDim.x + threadIdx.x;
  if (i < n) dst[i] = f2bf(src[i]);
}

// ---------------- block reduction helper (256 threads, 4 waves) ----------------
__device__ __forceinline__ float blk_sum(float v, float* s) {
  #pragma unroll
  for (int o = 32; o > 0; o >>= 1) v += __shfl_down(v, o, 64);
  int w = threadIdx.x >> 6;
  if ((threadIdx.x & 63) == 0) s[w] = v;
  __syncthreads();
  float r = s[0] + s[1] + s[2] + s[3];
  __syncthreads();
  return r;
}

// ---------------- embed gather + concat + LN0 ----------------
__global__ __launch_bounds__(256) void embed_ln0_k(
    const int* __restrict__ x, const int* __restrict__ qid,
    const float* __restrict__ emb, const float* __restrict__ qc,
    const float* __restrict__ g, const float* __restrict__ bta,
    float* __restrict__ item, unsigned short* __restrict__ item_bf)
{
  __shared__ float sbuf[4];
  int i = blockIdx.x;          // row (b*L + l)
  int t = threadIdx.x;         // 0..255, handles cols 4t..4t+3
  float4 v;
  if (t < 64) v = *(const float4*)&emb[(size_t)x[i] * 256 + t * 4];
  else        v = *(const float4*)&qc[(size_t)qid[i] * 768 + t * 4 - 256];
  float tot = blk_sum(v.x + v.y + v.z + v.w, sbuf);
  float mean = tot * (1.f / 1024.f);
  float dx = v.x - mean, dy = v.y - mean, dz = v.z - mean, dw = v.w - mean;
  float var = blk_sum(dx*dx + dy*dy + dz*dz + dw*dw, sbuf) * (1.f / 1024.f);
  float rstd = rsqrtf(var + 1e-12f);
  float vals[4] = {dx, dy, dz, dw};
  size_t rb = (size_t)i * 1024;
  #pragma unroll
  for (int j = 0; j < 4; j++) {
    int c = t * 4 + j;
    float o = vals[j] * rstd * g[c] + bta[c];
    item[rb + c] = o;
    item_bf[rb + c] = f2bf(o);
  }
}

// ---------------- generic bf16 GEMM: C[M,N] = A[M,K] * B[N,K]^T ----------------
// EPI 0: plain f32 store; EPI 1: sigmoid(acc + bias[col])
template <int EPI>
__global__ __launch_bounds__(256) void gemm_bt_k(
    const unsigned short* __restrict__ A, const unsigned short* __restrict__ Bw,
    float* __restrict__ C, const float* __restrict__ bias,
    int M, int N, int K)
{
  __shared__ __align__(16) unsigned short As[128][72];
  __shared__ __align__(16) unsigned short Bs[128][72];
  const int tid = threadIdx.x;
  const int m0 = blockIdx.x * 128;
  const int n0 = blockIdx.y * 128;
  const int w = tid >> 6, lane = tid & 63;
  const int wrow = (w >> 1) * 64, wcol = (w & 1) * 64;
  const int quad = lane >> 4, lid = lane & 15;
  const int lrow = tid >> 3;     // 0..31
  const int lchunk = tid & 7;    // 0..7

  f32x4 acc[4][4] = {};

  for (int k0 = 0; k0 < K; k0 += 64) {
    #pragma unroll
    for (int r = 0; r < 4; r++) {
      int row = r * 32 + lrow;
      uint4 av = *(const uint4*)&A[(size_t)(m0 + row) * K + k0 + lchunk * 8];
      *(uint4*)&As[row][lchunk * 8] = av;
      uint4 bv = make_uint4(0u, 0u, 0u, 0u);
      if (n0 + row < N)
        bv = *(const uint4*)&Bw[(size_t)(n0 + row) * K + k0 + lchunk * 8];
      *(uint4*)&Bs[row][lchunk * 8] = bv;
    }
    __syncthreads();
    #pragma unroll
    for (int kk = 0; kk < 64; kk += 32) {
      bf16x8 af[4], bfr[4];
      #pragma unroll
      for (int mi = 0; mi < 4; mi++)
        af[mi] = *(const bf16x8*)&As[wrow + mi * 16 + lid][kk + quad * 8];
      #pragma unroll
      for (int ni = 0; ni < 4; ni++)
        bfr[ni] = *(const bf16x8*)&Bs[wcol + ni * 16 + lid][kk + quad * 8];
      #pragma unroll
      for (int mi = 0; mi < 4; mi++)
        #pragma unroll
        for (int ni = 0; ni < 4; ni++)
          acc[mi][ni] = __builtin_amdgcn_mfma_f32_16x16x32_bf16(af[mi], bfr[ni], acc[mi][ni], 0, 0, 0);
    }
    __syncthreads();
  }

  #pragma unroll
  for (int mi = 0; mi < 4; mi++) {
    #pragma unroll
    for (int ni = 0; ni < 4; ni++) {
      int col = n0 + wcol + ni * 16 + lid;
      if (col >= N) continue;
      #pragma unroll
      for (int r = 0; r < 4; r++) {
        int row = m0 + wrow + mi * 16 + quad * 4 + r;
        float v = acc[mi][ni][r];
        if (EPI == 1) v = sigmoidf_(v + bias[col]);
        C[(size_t)row * N + col] = v;
      }
    }
  }
}

// ---------------- causal depthwise conv (K=4) + SiLU ----------------
__global__ void conv_silu_k(const float* __restrict__ u_r, const float* __restrict__ w,
                            const float* __restrict__ cb, float* __restrict__ uc,
                            unsigned short* __restrict__ uc_bf)
{
  int idx = blockIdx.x * blockDim.x + threadIdx.x;  // over B*L*DI
  if (idx >= BATCH * L_SEQ * DINNER) return;
  int d = idx & (DINNER - 1);
  int l = (idx >> 11) & (L_SEQ - 1);
  int b = idx >> 21;
  float4 wv = ((const float4*)w)[d];   // w[d][0..3]
  size_t rb = ((size_t)b * L_SEQ + l) * (2 * DINNER) + d;
  float acc = cb[d];
  acc += wv.w * u_r[rb];
  if (l >= 1) acc += wv.z * u_r[rb - (2 * DINNER)];
  if (l >= 2) acc += wv.y * u_r[rb - 2 * (2 * DINNER)];
  if (l >= 3) acc += wv.x * u_r[rb - 3 * (2 * DINNER)];
  float s = acc * sigmoidf_(acc);
  uc[idx] = s;
  uc_bf[idx] = f2bf(s);
}

// ---------------- dt slice -> bf16 ----------------
__global__ void dt_extract_k(const float* __restrict__ dbl, unsigned short* __restrict__ dt_bf)
{
  int i = blockIdx.x * blockDim.x + threadIdx.x;  // over 8192*64
  if (i >= NROWS * DTRANK) return;
  dt_bf[i] = f2bf(dbl[(size_t)(i >> 6) * 96 + (i & 63)]);
}

// ---------------- softplus(pre + bias) in-place ----------------
__global__ void softplus_k(float* dlt, const float* __restrict__ dtb)
{
  int i = blockIdx.x * blockDim.x + threadIdx.x;  // over 8192*2048
  if (i >= NROWS * DINNER) return;
  float xx = dlt[i] + dtb[i & (DINNER - 1)];
  dlt[i] = fmaxf(xx, 0.f) + log1pf(expf(-fabsf(xx)));
}

// ---------------- sequential selective scan ----------------
__global__ __launch_bounds__(64) void scan_k(
    float* dy,                              // in: delta, out: y (in-place)
    const float* __restrict__ u,
    const float* __restrict__ dblp,
    const float* __restrict__ Alog)
{
  int b = blockIdx.x >> 5;
  int d = ((blockIdx.x & 31) << 6) + threadIdx.x;
  float a2[NSTATE], h[NSTATE];
  #pragma unroll
  for (int n = 0; n < NSTATE; n++) {
    a2[n] = -expf(Alog[(size_t)d * NSTATE + n]) * 1.4426950408889634f;  // A * log2(e)
    h[n] = 0.f;
  }
  size_t base = ((size_t)b * L_SEQ) * DINNER + d;
  const float* bc = dblp + (size_t)b * L_SEQ * 96 + 64;  // [B(16) | C(16)] per step
  for (int t = 0; t < L_SEQ; t++) {
    float dl = dy[base];
    float ut = u[base];
    float du = dl * ut;
    float yv = 0.f;
    #pragma unroll
    for (int n = 0; n < NSTATE; n++) {
      float dA = exp2f(dl * a2[n]);
      h[n] = dA * h[n] + du * bc[n];
      yv += h[n] * bc[NSTATE + n];
    }
    dy[base] = yv;
    base += DINNER;
    bc += 96;
  }
}

// ---------------- gate: (y + u*D) * silu(r) -> bf16 ----------------
__global__ void gate_k(const float* __restrict__ y, const float* __restrict__ uc,
                       const float* __restrict__ u_r, const float* __restrict__ Dp,
                       unsigned short* __restrict__ y_bf)
{
  int idx = blockIdx.x * blockDim.x + threadIdx.x;  // over 8192*2048
  if (idx >= NROWS * DINNER) return;
  int d = idx & (DINNER - 1);
  int row = idx >> 11;
  float rv = u_r[(size_t)row * (2 * DINNER) + DINNER + d];
  float val = (y[idx] + uc[idx] * Dp[d]) * (rv * sigmoidf_(rv));
  y_bf[idx] = f2bf(val);
}

// ---------------- residual + LN1 -> bf16 ----------------
__global__ __launch_bounds__(256) void ln1_k(
    const float* __restrict__ mamba, const float* __restrict__ item,
    const float* __restrict__ g, const float* __restrict__ bta,
    unsigned short* __restrict__ out_bf)
{
  __shared__ float sbuf[4];
  int i = blockIdx.x;
  int t = threadIdx.x;
  size_t rb = (size_t)i * 1024 + t * 4;
  float4 v = *(const float4*)&mamba[rb];
  float4 w4 = *(const float4*)&item[rb];
  v.x += w4.x; v.y += w4.y; v.z += w4.z; v.w += w4.w;
  float tot = blk_sum(v.x + v.y + v.z + v.w, sbuf);
  float mean = tot * (1.f / 1024.f);
  float dx = v.x - mean, dy = v.y - mean, dz = v.z - mean, dw = v.w - mean;
  float var = blk_sum(dx*dx + dy*dy + dz*dz + dw*dw, sbuf) * (1.f / 1024.f);
  float rstd = rsqrtf(var + 1e-12f);
  float vals[4] = {dx, dy, dz, dw};
  #pragma unroll
  for (int j = 0; j < 4; j++) {
    int c = t * 4 + j;
    out_bf[(size_t)i * 1024 + c] = f2bf(vals[j] * rstd * g[c] + bta[c]);
  }
}

// ---------------- launch ----------------
extern "C" void kernel_launch(void* const* d_in, const int* in_sizes, int n_in,
                              void* d_out, int out_size, void* d_ws, size_t ws_size,
                              hipStream_t stream)
{
  (void)in_sizes; (void)n_in; (void)out_size; (void)ws_size;
  const int*   x     = (const int*)d_in[0];
  const int*   qid   = (const int*)d_in[1];
  const float* emb   = (const float*)d_in[2];
  const float* qc    = (const float*)d_in[3];
  const float* ln0g  = (const float*)d_in[4];
  const float* ln0b  = (const float*)d_in[5];
  const float* w_in  = (const float*)d_in[6];
  const float* convw = (const float*)d_in[7];
  const float* convb = (const float*)d_in[8];
  const float* w_x   = (const float*)d_in[9];
  const float* w_dt  = (const float*)d_in[10];
  const float* dtb   = (const float*)d_in[11];
  const float* Alog  = (const float*)d_in[12];
  const float* Dp    = (const float*)d_in[13];
  const float* w_out = (const float*)d_in[14];
  const float* ln1g  = (const float*)d_in[15];
  const float* ln1b  = (const float*)d_in[16];
  const float* w_fc  = (const float*)d_in[17];
  const float* fcb   = (const float*)d_in[18];
  float* out = (float*)d_out;

  char* base = (char*)d_ws;
  size_t off = 0;
  auto carve = [&](size_t bytes) -> char* {
    char* p = base + off;
    off = (off + bytes + 255) & ~(size_t)255;
    return p;
  };
  float* item  = (float*)carve((size_t)NROWS * 1024 * 4);
  float* u_r   = (float*)carve((size_t)NROWS * 4096 * 4);
  float* uc    = (float*)carve((size_t)NROWS * 2048 * 4);
  float* dbl   = (float*)carve((size_t)NROWS * 96 * 4);
  float* dlt   = (float*)carve((size_t)NROWS * 2048 * 4);
  float* mamba = (float*)carve((size_t)NROWS * 1024 * 4);
  unsigned short* bfbuf  = (unsigned short*)carve((size_t)NROWS * 2048 * 2);
  unsigned short* bw_in  = (unsigned short*)carve((size_t)4096 * 1024 * 2);
  unsigned short* bw_x   = (unsigned short*)carve((size_t)96 * 2048 * 2);
  unsigned short* bw_dt  = (unsigned short*)carve((size_t)2048 * 64 * 2);
  unsigned short* bw_out = (unsigned short*)carve((size_t)1024 * 2048 * 2);
  unsigned short* bw_fc  = (unsigned short*)carve((size_t)4000 * 1024 * 2);

  auto cv = [&](const float* s, unsigned short* dst, int n) {
    cast_bf16_k<<<(n + 255) / 256, 256, 0, stream>>>(s, dst, n);
  };
  cv(w_in,  bw_in,  4096 * 1024);
  cv(w_x,   bw_x,   96 * 2048);
  cv(w_dt,  bw_dt,  2048 * 64);
  cv(w_out, bw_out, 1024 * 2048);
  cv(w_fc,  bw_fc,  4000 * 1024);

  // 1. embedding gather + concat + LN0
  embed_ln0_k<<<NROWS, 256, 0, stream>>>(x, qid, emb, qc, ln0g, ln0b, item, bfbuf);

  // 2. in_proj: (8192,1024) x (4096,1024)^T -> u_r
  gemm_bt_k<0><<<dim3(64, 32), 256, 0, stream>>>(bfbuf, bw_in, u_r, nullptr, NROWS, 4096, 1024);

  // 3. conv + silu
  conv_silu_k<<<(NROWS * DINNER) / 256, 256, 0, stream>>>(u_r, convw, convb, uc, bfbuf);

  // 4. x_proj: (8192,2048) x (96,2048)^T -> dbl
  gemm_bt_k<0><<<dim3(64, 1), 256, 0, stream>>>(bfbuf, bw_x, dbl, nullptr, NROWS, 96, 2048);

  // 5. dt slice -> bf16
  dt_extract_k<<<(NROWS * DTRANK) / 256, 256, 0, stream>>>(dbl, bfbuf);

  // 6. dt_proj: (8192,64) x (2048,64)^T -> dlt (pre-softplus)
  gemm_bt_k<0><<<dim3(64, 16), 256, 0, stream>>>(bfbuf, bw_dt, dlt, nullptr, NROWS, 2048, 64);

  // 7. softplus(+bias) in place
  softplus_k<<<(NROWS * DINNER) / 256, 256, 0, stream>>>(dlt, dtb);

  // 8. selective scan (delta -> y in place)
  scan_k<<<BATCH * 32, 64, 0, stream>>>(dlt, uc, dbl, Alog);

  // 9. gate -> bf16
  gate_k<<<(NROWS * DINNER) / 256, 256, 0, stream>>>(dlt, uc, u_r, Dp, bfbuf);

  // 10. out_proj: (8192,2048) x (1024,2048)^T -> mamba
  gemm_bt_k<0><<<dim3(64, 8), 256, 0, stream>>>(bfbuf, bw_out, mamba, nullptr, NROWS, 1024, 2048);

  // 11. residual + LN1 -> bf16
  ln1_k<<<NROWS, 256, 0, stream>>>(mamba, item, ln1g, ln1b, bfbuf);

  // 12. fc + sigmoid -> out
  gemm_bt_k<1><<<dim3(64, 32), 256, 0, stream>>>(bfbuf, bw_fc, out, fcb, NROWS, 4000, 1024);
}

// Round 2
// 1053.105 us; speedup vs baseline: 1.4308x; 1.4308x over previous
//
#include <hip/hip_runtime.h>
#include <cstdint>
#include <cstddef>

#define L_SEQ 1024
#define BATCH 8
#define DMODEL 1024
#define DINNER 2048
#define NSTATE 16
#define DTRANK 64
#define NQ 4000
#define NROWS (BATCH * L_SEQ)   // 8192
#define CH 32                   // scan chunk length
#define NCH (L_SEQ / CH)        // 32 chunks

typedef float f32x4 __attribute__((ext_vector_type(4)));
typedef __bf16 bf16x8 __attribute__((ext_vector_type(8)));

__device__ __forceinline__ unsigned short f2bf(float f) {
  union { float f; unsigned int u; } c; c.f = f;
  unsigned int u = c.u;
  unsigned int r = u + 0x7fffu + ((u >> 16) & 1u);
  return (unsigned short)(r >> 16);
}

__device__ __forceinline__ float sigmoidf_(float x) { return 1.f / (1.f + expf(-x)); }

// ---------------- weight fp32 -> bf16 cast ----------------
__global__ void cast_bf16_k(const float* __restrict__ src, unsigned short* __restrict__ dst, int n) {
  int i = blockIdx.x * blockDim.x + threadIdx.x;
  if (i < n) dst[i] = f2bf(src[i]);
}

// ---------------- block reduction helper (256 threads, 4 waves) ----------------
__device__ __forceinline__ float blk_sum(float v, float* s) {
  #pragma unroll
  for (int o = 32; o > 0; o >>= 1) v += __shfl_down(v, o, 64);
  int w = threadIdx.x >> 6;
  if ((threadIdx.x & 63) == 0) s[w] = v;
  __syncthreads();
  float r = s[0] + s[1] + s[2] + s[3];
  __syncthreads();
  return r;
}

// ---------------- embed gather + concat + LN0 ----------------
__global__ __launch_bounds__(256) void embed_ln0_k(
    const int* __restrict__ x, const int* __restrict__ qid,
    const float* __restrict__ emb, const float* __restrict__ qc,
    const float* __restrict__ g, const float* __restrict__ bta,
    float* __restrict__ item, unsigned short* __restrict__ item_bf)
{
  __shared__ float sbuf[4];
  int i = blockIdx.x;          // row (b*L + l)
  int t = threadIdx.x;         // 0..255, handles cols 4t..4t+3
  float4 v;
  if (t < 64) v = *(const float4*)&emb[(size_t)x[i] * 256 + t * 4];
  else        v = *(const float4*)&qc[(size_t)qid[i] * 768 + t * 4 - 256];
  float tot = blk_sum(v.x + v.y + v.z + v.w, sbuf);
  float mean = tot * (1.f / 1024.f);
  float dx = v.x - mean, dy = v.y - mean, dz = v.z - mean, dw = v.w - mean;
  float var = blk_sum(dx*dx + dy*dy + dz*dz + dw*dw, sbuf) * (1.f / 1024.f);
  float rstd = rsqrtf(var + 1e-12f);
  float vals[4] = {dx, dy, dz, dw};
  size_t rb = (size_t)i * 1024;
  #pragma unroll
  for (int j = 0; j < 4; j++) {
    int c = t * 4 + j;
    float o = vals[j] * rstd * g[c] + bta[c];
    item[rb + c] = o;
    item_bf[rb + c] = f2bf(o);
  }
}

// ---------------- generic bf16 GEMM: C[M,N] = A[M,K] * B[N,K]^T ----------------
// EPI 0: plain f32 store; EPI 1: sigmoid(acc + bias[col])
template <int EPI>
__global__ __launch_bounds__(256) void gemm_bt_k(
    const unsigned short* __restrict__ A, const unsigned short* __restrict__ Bw,
    float* __restrict__ C, const float* __restrict__ bias,
    int M, int N, int K)
{
  __shared__ __align__(16) unsigned short As[128][72];
  __shared__ __align__(16) unsigned short Bs[128][72];
  const int tid = threadIdx.x;
  const int m0 = blockIdx.x * 128;
  const int n0 = blockIdx.y * 128;
  const int w = tid >> 6, lane = tid & 63;
  const int wrow = (w >> 1) * 64, wcol = (w & 1) * 64;
  const int quad = lane >> 4, lid = lane & 15;
  const int lrow = tid >> 3;     // 0..31
  const int lchunk = tid & 7;    // 0..7

  f32x4 acc[4][4] = {};

  for (int k0 = 0; k0 < K; k0 += 64) {
    #pragma unroll
    for (int r = 0; r < 4; r++) {
      int row = r * 32 + lrow;
      uint4 av = *(const uint4*)&A[(size_t)(m0 + row) * K + k0 + lchunk * 8];
      *(uint4*)&As[row][lchunk * 8] = av;
      uint4 bv = make_uint4(0u, 0u, 0u, 0u);
      if (n0 + row < N)
        bv = *(const uint4*)&Bw[(size_t)(n0 + row) * K + k0 + lchunk * 8];
      *(uint4*)&Bs[row][lchunk * 8] = bv;
    }
    __syncthreads();
    #pragma unroll
    for (int kk = 0; kk < 64; kk += 32) {
      bf16x8 af[4], bfr[4];
      #pragma unroll
      for (int mi = 0; mi < 4; mi++)
        af[mi] = *(const bf16x8*)&As[wrow + mi * 16 + lid][kk + quad * 8];
      #pragma unroll
      for (int ni = 0; ni < 4; ni++)
        bfr[ni] = *(const bf16x8*)&Bs[wcol + ni * 16 + lid][kk + quad * 8];
      #pragma unroll
      for (int mi = 0; mi < 4; mi++)
        #pragma unroll
        for (int ni = 0; ni < 4; ni++)
          acc[mi][ni] = __builtin_amdgcn_mfma_f32_16x16x32_bf16(af[mi], bfr[ni], acc[mi][ni], 0, 0, 0);
    }
    __syncthreads();
  }

  #pragma unroll
  for (int mi = 0; mi < 4; mi++) {
    #pragma unroll
    for (int ni = 0; ni < 4; ni++) {
      int col = n0 + wcol + ni * 16 + lid;
      if (col >= N) continue;
      #pragma unroll
      for (int r = 0; r < 4; r++) {
        int row = m0 + wrow + mi * 16 + quad * 4 + r;
        float v = acc[mi][ni][r];
        if (EPI == 1) v = sigmoidf_(v + bias[col]);
        C[(size_t)row * N + col] = v;
      }
    }
  }
}

// ---------------- causal depthwise conv (K=4) + SiLU ----------------
__global__ void conv_silu_k(const float* __restrict__ u_r, const float* __restrict__ w,
                            const float* __restrict__ cb, float* __restrict__ uc,
                            unsigned short* __restrict__ uc_bf)
{
  int idx = blockIdx.x * blockDim.x + threadIdx.x;  // over B*L*DI
  if (idx >= BATCH * L_SEQ * DINNER) return;
  int d = idx & (DINNER - 1);
  int l = (idx >> 11) & (L_SEQ - 1);
  int b = idx >> 21;
  float4 wv = ((const float4*)w)[d];   // w[d][0..3]
  size_t rb = ((size_t)b * L_SEQ + l) * (2 * DINNER) + d;
  float acc = cb[d];
  acc += wv.w * u_r[rb];
  if (l >= 1) acc += wv.z * u_r[rb - (2 * DINNER)];
  if (l >= 2) acc += wv.y * u_r[rb - 2 * (2 * DINNER)];
  if (l >= 3) acc += wv.x * u_r[rb - 3 * (2 * DINNER)];
  float s = acc * sigmoidf_(acc);
  uc[idx] = s;
  uc_bf[idx] = f2bf(s);
}

// ---------------- dt slice -> bf16 ----------------
__global__ void dt_extract_k(const float* __restrict__ dbl, unsigned short* __restrict__ dt_bf)
{
  int i = blockIdx.x * blockDim.x + threadIdx.x;  // over 8192*64
  if (i >= NROWS * DTRANK) return;
  dt_bf[i] = f2bf(dbl[(size_t)(i >> 6) * 96 + (i & 63)]);
}

// ---------------- softplus(pre + bias) in-place ----------------
__global__ void softplus_k(float* dlt, const float* __restrict__ dtb)
{
  int i = blockIdx.x * blockDim.x + threadIdx.x;  // over 8192*2048
  if (i >= NROWS * DINNER) return;
  float xx = dlt[i] + dtb[i & (DINNER - 1)];
  dlt[i] = fmaxf(xx, 0.f) + log1pf(expf(-fabsf(xx)));
}

// ---------------- A2 precompute: a2t[n][d] = -exp(A_log[d][n]) * log2(e) ----------------
__global__ void a2_k(const float* __restrict__ Alog, float* __restrict__ a2t)
{
  int i = blockIdx.x * blockDim.x + threadIdx.x;   // over 2048*16
  if (i >= DINNER * NSTATE) return;
  int d = i >> 4, n = i & 15;
  a2t[n * DINNER + d] = -expf(Alog[i]) * 1.4426950408889634f;
}

// ---------------- chunked scan pass 1: per-chunk aggregates (P, q) with h0=0 ----------------
__global__ __launch_bounds__(64) void scan1_k(
    const float* __restrict__ dlt, const float* __restrict__ uc,
    const float* __restrict__ dbl, const float* __restrict__ a2t,
    float* __restrict__ Pbuf, float* __restrict__ Qbuf)
{
  int c = blockIdx.x;            // chunk
  int dg = blockIdx.y;           // d-group of 64
  int b = blockIdx.z;
  int d = dg * 64 + threadIdx.x;
  float a2[NSTATE], P[NSTATE], q[NSTATE];
  #pragma unroll
  for (int n = 0; n < NSTATE; n++) {
    a2[n] = a2t[n * DINNER + d];
    P[n] = 1.f; q[n] = 0.f;
  }
  size_t base = ((size_t)(b * L_SEQ + c * CH)) * DINNER + d;
  const float* bc = dbl + (size_t)(b * L_SEQ + c * CH) * 96 + 64;
  for (int t = 0; t < CH; t++) {
    float dl = dlt[base];
    float du = dl * uc[base];
    #pragma unroll
    for (int n = 0; n < NSTATE; n++) {
      float dA = exp2f(dl * a2[n]);
      q[n] = dA * q[n] + du * bc[n];
      P[n] *= dA;
    }
    base += DINNER;
    bc += 96;
  }
  size_t ob = ((size_t)((b * NCH + c) * NSTATE)) * DINNER + d;
  #pragma unroll
  for (int n = 0; n < NSTATE; n++) {
    Pbuf[ob + (size_t)n * DINNER] = P[n];
    Qbuf[ob + (size_t)n * DINNER] = q[n];
  }
}

// ---------------- chunked scan carry: sequential combine over chunks ----------------
// After this kernel Qbuf[b][c][n][d] holds h_init (state BEFORE chunk c).
__global__ void scan_carry_k(const float* __restrict__ Pbuf, float* __restrict__ Qbuf)
{
  int idx = blockIdx.x * blockDim.x + threadIdx.x;  // over 8*16*2048 = 262144
  if (idx >= BATCH * NSTATE * DINNER) return;
  int d = idx & (DINNER - 1);
  int n = (idx >> 11) & 15;
  int b = idx >> 15;
  float h = 0.f;
  for (int c = 0; c < NCH; c++) {
    size_t o = ((size_t)((b * NCH + c) * NSTATE + n)) * DINNER + d;
    float P = Pbuf[o];
    float q = Qbuf[o];
    Qbuf[o] = h;
    h = P * h + q;
  }
}

// ---------------- chunked scan pass 2: replay with true h_init, emit y ----------------
__global__ __launch_bounds__(64) void scan2_k(
    float* __restrict__ dlt,               // in: delta, out: y (in-place)
    const float* __restrict__ uc,
    const float* __restrict__ dbl, const float* __restrict__ a2t,
    const float* __restrict__ Qbuf)
{
  int c = blockIdx.x;
  int dg = blockIdx.y;
  int b = blockIdx.z;
  int d = dg * 64 + threadIdx.x;
  float a2[NSTATE], h[NSTATE];
  size_t ob = ((size_t)((b * NCH + c) * NSTATE)) * DINNER + d;
  #pragma unroll
  for (int n = 0; n < NSTATE; n++) {
    a2[n] = a2t[n * DINNER + d];
    h[n] = Qbuf[ob + (size_t)n * DINNER];
  }
  size_t base = ((size_t)(b * L_SEQ + c * CH)) * DINNER + d;
  const float* bc = dbl + (size_t)(b * L_SEQ + c * CH) * 96 + 64;
  for (int t = 0; t < CH; t++) {
    float dl = dlt[base];
    float du = dl * uc[base];
    float yv = 0.f;
    #pragma unroll
    for (int n = 0; n < NSTATE; n++) {
      float dA = exp2f(dl * a2[n]);
      h[n] = dA * h[n] + du * bc[n];
      yv += h[n] * bc[NSTATE + n];
    }
    dlt[base] = yv;
    base += DINNER;
    bc += 96;
  }
}

// ---------------- gate: (y + u*D) * silu(r) -> bf16 ----------------
__global__ void gate_k(const float* __restrict__ y, const float* __restrict__ uc,
                       const float* __restrict__ u_r, const float* __restrict__ Dp,
                       unsigned short* __restrict__ y_bf)
{
  int idx = blockIdx.x * blockDim.x + threadIdx.x;  // over 8192*2048
  if (idx >= NROWS * DINNER) return;
  int d = idx & (DINNER - 1);
  int row = idx >> 11;
  float rv = u_r[(size_t)row * (2 * DINNER) + DINNER + d];
  float val = (y[idx] + uc[idx] * Dp[d]) * (rv * sigmoidf_(rv));
  y_bf[idx] = f2bf(val);
}

// ---------------- residual + LN1 -> bf16 ----------------
__global__ __launch_bounds__(256) void ln1_k(
    const float* __restrict__ mamba, const float* __restrict__ item,
    const float* __restrict__ g, const float* __restrict__ bta,
    unsigned short* __restrict__ out_bf)
{
  __shared__ float sbuf[4];
  int i = blockIdx.x;
  int t = threadIdx.x;
  size_t rb = (size_t)i * 1024 + t * 4;
  float4 v = *(const float4*)&mamba[rb];
  float4 w4 = *(const float4*)&item[rb];
  v.x += w4.x; v.y += w4.y; v.z += w4.z; v.w += w4.w;
  float tot = blk_sum(v.x + v.y + v.z + v.w, sbuf);
  float mean = tot * (1.f / 1024.f);
  float dx = v.x - mean, dy = v.y - mean, dz = v.z - mean, dw = v.w - mean;
  float var = blk_sum(dx*dx + dy*dy + dz*dz + dw*dw, sbuf) * (1.f / 1024.f);
  float rstd = rsqrtf(var + 1e-12f);
  float vals[4] = {dx, dy, dz, dw};
  #pragma unroll
  for (int j = 0; j < 4; j++) {
    int c = t * 4 + j;
    out_bf[(size_t)i * 1024 + c] = f2bf(vals[j] * rstd * g[c] + bta[c]);
  }
}

// ---------------- launch ----------------
extern "C" void kernel_launch(void* const* d_in, const int* in_sizes, int n_in,
                              void* d_out, int out_size, void* d_ws, size_t ws_size,
                              hipStream_t stream)
{
  (void)in_sizes; (void)n_in; (void)out_size; (void)ws_size;
  const int*   x     = (const int*)d_in[0];
  const int*   qid   = (const int*)d_in[1];
  const float* emb   = (const float*)d_in[2];
  const float* qc    = (const float*)d_in[3];
  const float* ln0g  = (const float*)d_in[4];
  const float* ln0b  = (const float*)d_in[5];
  const float* w_in  = (const float*)d_in[6];
  const float* convw = (const float*)d_in[7];
  const float* convb = (const float*)d_in[8];
  const float* w_x   = (const float*)d_in[9];
  const float* w_dt  = (const float*)d_in[10];
  const float* dtb   = (const float*)d_in[11];
  const float* Alog  = (const float*)d_in[12];
  const float* Dp    = (const float*)d_in[13];
  const float* w_out = (const float*)d_in[14];
  const float* ln1g  = (const float*)d_in[15];
  const float* ln1b  = (const float*)d_in[16];
  const float* w_fc  = (const float*)d_in[17];
  const float* fcb   = (const float*)d_in[18];
  float* out = (float*)d_out;

  char* base = (char*)d_ws;
  size_t off = 0;
  auto carve = [&](size_t bytes) -> char* {
    char* p = base + off;
    off = (off + bytes + 255) & ~(size_t)255;
    return p;
  };
  float* item  = (float*)carve((size_t)NROWS * 1024 * 4);
  float* u_r   = (float*)carve((size_t)NROWS * 4096 * 4);
  float* uc    = (float*)carve((size_t)NROWS * 2048 * 4);
  float* dbl   = (float*)carve((size_t)NROWS * 96 * 4);
  float* dlt   = (float*)carve((size_t)NROWS * 2048 * 4);
  float* mamba = (float*)carve((size_t)NROWS * 1024 * 4);
  unsigned short* bfbuf  = (unsigned short*)carve((size_t)NROWS * 2048 * 2);
  unsigned short* bw_in  = (unsigned short*)carve((size_t)4096 * 1024 * 2);
  unsigned short* bw_x   = (unsigned short*)carve((size_t)96 * 2048 * 2);
  unsigned short* bw_dt  = (unsigned short*)carve((size_t)2048 * 64 * 2);
  unsigned short* bw_out = (unsigned short*)carve((size_t)1024 * 2048 * 2);
  unsigned short* bw_fc  = (unsigned short*)carve((size_t)4000 * 1024 * 2);
  float* a2t   = (float*)carve((size_t)DINNER * NSTATE * 4);

  // Scan scratch aliases buffers that are dead during the scan window:
  //   Pbuf <- mamba  (written only later by out_proj GEMM)   33.5 MB exact
  //   Qbuf <- bfbuf  (dt_bf consumed by dt_proj GEMM before)  33.5 MB exact
  float* Pbuf = mamba;
  float* Qbuf = (float*)bfbuf;

  auto cv = [&](const float* s, unsigned short* dst, int n) {
    cast_bf16_k<<<(n + 255) / 256, 256, 0, stream>>>(s, dst, n);
  };
  cv(w_in,  bw_in,  4096 * 1024);
  cv(w_x,   bw_x,   96 * 2048);
  cv(w_dt,  bw_dt,  2048 * 64);
  cv(w_out, bw_out, 1024 * 2048);
  cv(w_fc,  bw_fc,  4000 * 1024);
  a2_k<<<(DINNER * NSTATE + 255) / 256, 256, 0, stream>>>(Alog, a2t);

  // 1. embedding gather + concat + LN0
  embed_ln0_k<<<NROWS, 256, 0, stream>>>(x, qid, emb, qc, ln0g, ln0b, item, bfbuf);

  // 2. in_proj: (8192,1024) x (4096,1024)^T -> u_r
  gemm_bt_k<0><<<dim3(64, 32), 256, 0, stream>>>(bfbuf, bw_in, u_r, nullptr, NROWS, 4096, 1024);

  // 3. conv + silu
  conv_silu_k<<<(NROWS * DINNER) / 256, 256, 0, stream>>>(u_r, convw, convb, uc, bfbuf);

  // 4. x_proj: (8192,2048) x (96,2048)^T -> dbl
  gemm_bt_k<0><<<dim3(64, 1), 256, 0, stream>>>(bfbuf, bw_x, dbl, nullptr, NROWS, 96, 2048);

  // 5. dt slice -> bf16
  dt_extract_k<<<(NROWS * DTRANK) / 256, 256, 0, stream>>>(dbl, bfbuf);

  // 6. dt_proj: (8192,64) x (2048,64)^T -> dlt (pre-softplus)
  gemm_bt_k<0><<<dim3(64, 16), 256, 0, stream>>>(bfbuf, bw_dt, dlt, nullptr, NROWS, 2048, 64);

  // 7. softplus(+bias) in place
  softplus_k<<<(NROWS * DINNER) / 256, 256, 0, stream>>>(dlt, dtb);

  // 8. chunked selective scan (delta -> y in place)
  scan1_k<<<dim3(NCH, 32, BATCH), 64, 0, stream>>>(dlt, uc, dbl, a2t, Pbuf, Qbuf);
  scan_carry_k<<<(BATCH * NSTATE * DINNER) / 256, 256, 0, stream>>>(Pbuf, Qbuf);
  scan2_k<<<dim3(NCH, 32, BATCH), 64, 0, stream>>>(dlt, uc, dbl, a2t, Qbuf);

  // 9. gate -> bf16 (overwrites bfbuf; Qbuf dead from here)
  gate_k<<<(NROWS * DINNER) / 256, 256, 0, stream>>>(dlt, uc, u_r, Dp, bfbuf);

  // 10. out_proj: (8192,2048) x (1024,2048)^T -> mamba (overwrites Pbuf; dead)
  gemm_bt_k<0><<<dim3(64, 8), 256, 0, stream>>>(bfbuf, bw_out, mamba, nullptr, NROWS, 1024, 2048);

  // 11. residual + LN1 -> bf16
  ln1_k<<<NROWS, 256, 0, stream>>>(mamba, item, ln1g, ln1b, bfbuf);

  // 12. fc + sigmoid -> out
  gemm_bt_k<1><<<dim3(64, 32), 256, 0, stream>>>(bfbuf, bw_fc, out, fcb, NROWS, 4000, 1024);
}

// Round 3
// 892.987 us; speedup vs baseline: 1.6874x; 1.1793x over previous
//
#include <hip/hip_runtime.h>
#include <cstdint>
#include <cstddef>

#define L_SEQ 1024
#define BATCH 8
#define DMODEL 1024
#define DINNER 2048
#define NSTATE 16
#define DTRANK 64
#define NQ 4000
#define NROWS (BATCH * L_SEQ)   // 8192
#define CH 32                   // scan chunk length
#define NCH (L_SEQ / CH)        // 32 chunks

typedef float f32x4 __attribute__((ext_vector_type(4)));
typedef __bf16 bf16x8 __attribute__((ext_vector_type(8)));

#define AS1 __attribute__((address_space(1)))
#define AS3 __attribute__((address_space(3)))

__device__ __forceinline__ unsigned short f2bf(float f) {
  union { float f; unsigned int u; } c; c.f = f;
  unsigned int u = c.u;
  unsigned int r = u + 0x7fffu + ((u >> 16) & 1u);
  return (unsigned short)(r >> 16);
}

__device__ __forceinline__ float sigmoidf_(float x) { return 1.f / (1.f + expf(-x)); }

// ---------------- weight fp32 -> bf16 cast ----------------
__global__ void cast_bf16_k(const float* __restrict__ src, unsigned short* __restrict__ dst, int n) {
  int i = blockIdx.x * blockDim.x + threadIdx.x;
  if (i < n) dst[i] = f2bf(src[i]);
}

// ---------------- block reduction helper (256 threads, 4 waves) ----------------
__device__ __forceinline__ float blk_sum(float v, float* s) {
  #pragma unroll
  for (int o = 32; o > 0; o >>= 1) v += __shfl_down(v, o, 64);
  int w = threadIdx.x >> 6;
  if ((threadIdx.x & 63) == 0) s[w] = v;
  __syncthreads();
  float r = s[0] + s[1] + s[2] + s[3];
  __syncthreads();
  return r;
}

// ---------------- embed gather + concat + LN0 ----------------
__global__ __launch_bounds__(256) void embed_ln0_k(
    const int* __restrict__ x, const int* __restrict__ qid,
    const float* __restrict__ emb, const float* __restrict__ qc,
    const float* __restrict__ g, const float* __restrict__ bta,
    float* __restrict__ item, unsigned short* __restrict__ item_bf)
{
  __shared__ float sbuf[4];
  int i = blockIdx.x;          // row (b*L + l)
  int t = threadIdx.x;         // 0..255, handles cols 4t..4t+3
  float4 v;
  if (t < 64) v = *(const float4*)&emb[(size_t)x[i] * 256 + t * 4];
  else        v = *(const float4*)&qc[(size_t)qid[i] * 768 + t * 4 - 256];
  float tot = blk_sum(v.x + v.y + v.z + v.w, sbuf);
  float mean = tot * (1.f / 1024.f);
  float dx = v.x - mean, dy = v.y - mean, dz = v.z - mean, dw = v.w - mean;
  float var = blk_sum(dx*dx + dy*dy + dz*dz + dw*dw, sbuf) * (1.f / 1024.f);
  float rstd = rsqrtf(var + 1e-12f);
  float vals[4] = {dx, dy, dz, dw};
  size_t rb = (size_t)i * 1024;
  #pragma unroll
  for (int j = 0; j < 4; j++) {
    int c = t * 4 + j;
    float o = vals[j] * rstd * g[c] + bta[c];
    item[rb + c] = o;
    item_bf[rb + c] = f2bf(o);
  }
}

// ---------------- bf16 GEMM via global_load_lds + XOR-swizzled LDS ----------------
// C[M,N] = A[M,K] * B[N,K]^T.  EPI 0: f32 store; EPI 1: sigmoid(acc + bias[col]).
// LDS layout: tile[row][slot] (8 slots of 8 bf16); slot s of row r holds k-chunk
// s ^ (r&7).  Staging: lane l of an 8-row issue fetches chunk (l&7)^(l>>3) of row
// l>>3, so global access stays coalesced (full 128B row segments) while LDS reads
// are conflict-free.
template <int EPI>
__global__ __launch_bounds__(256) void gemm_bt_k(
    const unsigned short* __restrict__ A, const unsigned short* __restrict__ Bw,
    float* __restrict__ C, const float* __restrict__ bias,
    int M, int N, int K)
{
  __shared__ __align__(16) unsigned short As[128 * 64];
  __shared__ __align__(16) unsigned short Bs[128 * 64];
  const int tid = threadIdx.x;
  const int m0 = blockIdx.x * 128;
  const int n0 = blockIdx.y * 128;
  const int w = tid >> 6, lane = tid & 63;
  const int wrow = (w >> 1) * 64, wcol = (w & 1) * 64;
  const int quad = lane >> 4, lid = lane & 15;

  // staging geometry
  const int srow = lane >> 3;                  // 0..7
  const int schunk = (lane & 7) ^ srow;        // swizzled k-chunk for this lane

  // per-lane global element offsets (row part varies by issue i via += 32*K)
  const unsigned short* Abase = A + (size_t)(m0 + w * 8 + srow) * K + schunk * 8;
  // B rows clamped to N-1 (garbage lands in cols >= N, never stored)
  const unsigned short* Bbase[4];
  #pragma unroll
  for (int i = 0; i < 4; i++) {
    int rB = n0 + w * 8 + i * 32 + srow;
    if (rB > N - 1) rB = N - 1;
    Bbase[i] = Bw + (size_t)rB * K + schunk * 8;
  }

  f32x4 acc[4][4] = {};

  for (int k0 = 0; k0 < K; k0 += 64) {
    #pragma unroll
    for (int i = 0; i < 4; i++) {
      int rA = w * 8 + i * 32;   // wave-uniform LDS row-group base
      __builtin_amdgcn_global_load_lds(
          (const AS1 unsigned int*)(Abase + (size_t)i * 32 * K + k0),
          (AS3 unsigned int*)&As[rA * 64], 16, 0, 0);
      __builtin_amdgcn_global_load_lds(
          (const AS1 unsigned int*)(Bbase[i] + k0),
          (AS3 unsigned int*)&Bs[rA * 64], 16, 0, 0);
    }
    __syncthreads();
    #pragma unroll
    for (int kk = 0; kk < 64; kk += 32) {
      bf16x8 af[4], bfr[4];
      #pragma unroll
      for (int mi = 0; mi < 4; mi++) {
        int r = wrow + mi * 16 + lid;
        int slot = ((kk >> 3) + quad) ^ (lid & 7);
        af[mi] = *(const bf16x8*)&As[r * 64 + slot * 8];
      }
      #pragma unroll
      for (int ni = 0; ni < 4; ni++) {
        int r = wcol + ni * 16 + lid;
        int slot = ((kk >> 3) + quad) ^ (lid & 7);
        bfr[ni] = *(const bf16x8*)&Bs[r * 64 + slot * 8];
      }
      #pragma unroll
      for (int mi = 0; mi < 4; mi++)
        #pragma unroll
        for (int ni = 0; ni < 4; ni++)
          acc[mi][ni] = __builtin_amdgcn_mfma_f32_16x16x32_bf16(af[mi], bfr[ni], acc[mi][ni], 0, 0, 0);
    }
    __syncthreads();
  }

  #pragma unroll
  for (int mi = 0; mi < 4; mi++) {
    #pragma unroll
    for (int ni = 0; ni < 4; ni++) {
      int col = n0 + wcol + ni * 16 + lid;
      if (col >= N) continue;
      #pragma unroll
      for (int r = 0; r < 4; r++) {
        int row = m0 + wrow + mi * 16 + quad * 4 + r;
        float v = acc[mi][ni][r];
        if (EPI == 1) v = sigmoidf_(v + bias[col]);
        C[(size_t)row * N + col] = v;
      }
    }
  }
}

// ---------------- causal depthwise conv (K=4) + SiLU ----------------
__global__ void conv_silu_k(const float* __restrict__ u_r, const float* __restrict__ w,
                            const float* __restrict__ cb, float* __restrict__ uc,
                            unsigned short* __restrict__ uc_bf)
{
  int idx = blockIdx.x * blockDim.x + threadIdx.x;  // over B*L*DI
  if (idx >= BATCH * L_SEQ * DINNER) return;
  int d = idx & (DINNER - 1);
  int l = (idx >> 11) & (L_SEQ - 1);
  int b = idx >> 21;
  float4 wv = ((const float4*)w)[d];   // w[d][0..3]
  size_t rb = ((size_t)b * L_SEQ + l) * (2 * DINNER) + d;
  float acc = cb[d];
  acc += wv.w * u_r[rb];
  if (l >= 1) acc += wv.z * u_r[rb - (2 * DINNER)];
  if (l >= 2) acc += wv.y * u_r[rb - 2 * (2 * DINNER)];
  if (l >= 3) acc += wv.x * u_r[rb - 3 * (2 * DINNER)];
  float s = acc * sigmoidf_(acc);
  uc[idx] = s;
  uc_bf[idx] = f2bf(s);
}

// ---------------- dt slice -> bf16 ----------------
__global__ void dt_extract_k(const float* __restrict__ dbl, unsigned short* __restrict__ dt_bf)
{
  int i = blockIdx.x * blockDim.x + threadIdx.x;  // over 8192*64
  if (i >= NROWS * DTRANK) return;
  dt_bf[i] = f2bf(dbl[(size_t)(i >> 6) * 96 + (i & 63)]);
}

// ---------------- softplus(pre + bias) in-place ----------------
__global__ void softplus_k(float* dlt, const float* __restrict__ dtb)
{
  int i = blockIdx.x * blockDim.x + threadIdx.x;  // over 8192*2048
  if (i >= NROWS * DINNER) return;
  float xx = dlt[i] + dtb[i & (DINNER - 1)];
  dlt[i] = fmaxf(xx, 0.f) + log1pf(expf(-fabsf(xx)));
}

// ---------------- A2 precompute: a2t[n][d] = -exp(A_log[d][n]) * log2(e) ----------------
__global__ void a2_k(const float* __restrict__ Alog, float* __restrict__ a2t)
{
  int i = blockIdx.x * blockDim.x + threadIdx.x;   // over 2048*16
  if (i >= DINNER * NSTATE) return;
  int d = i >> 4, n = i & 15;
  a2t[n * DINNER + d] = -expf(Alog[i]) * 1.4426950408889634f;
}

// ---------------- chunked scan pass 1: per-chunk aggregates (P, q) with h0=0 ----------------
__global__ __launch_bounds__(64) void scan1_k(
    const float* __restrict__ dlt, const float* __restrict__ uc,
    const float* __restrict__ dbl, const float* __restrict__ a2t,
    float* __restrict__ Pbuf, float* __restrict__ Qbuf)
{
  int c = blockIdx.x;            // chunk
  int dg = blockIdx.y;           // d-group of 64
  int b = blockIdx.z;
  int d = dg * 64 + threadIdx.x;
  float a2[NSTATE], P[NSTATE], q[NSTATE];
  #pragma unroll
  for (int n = 0; n < NSTATE; n++) {
    a2[n] = a2t[n * DINNER + d];
    P[n] = 1.f; q[n] = 0.f;
  }
  size_t base = ((size_t)(b * L_SEQ + c * CH)) * DINNER + d;
  const float* bc = dbl + (size_t)(b * L_SEQ + c * CH) * 96 + 64;
  for (int t = 0; t < CH; t++) {
    float dl = dlt[base];
    float du = dl * uc[base];
    #pragma unroll
    for (int n = 0; n < NSTATE; n++) {
      float dA = exp2f(dl * a2[n]);
      q[n] = dA * q[n] + du * bc[n];
      P[n] *= dA;
    }
    base += DINNER;
    bc += 96;
  }
  size_t ob = ((size_t)((b * NCH + c) * NSTATE)) * DINNER + d;
  #pragma unroll
  for (int n = 0; n < NSTATE; n++) {
    Pbuf[ob + (size_t)n * DINNER] = P[n];
    Qbuf[ob + (size_t)n * DINNER] = q[n];
  }
}

// ---------------- chunked scan carry: sequential combine over chunks ----------------
// After this kernel Qbuf[b][c][n][d] holds h_init (state BEFORE chunk c).
__global__ void scan_carry_k(const float* __restrict__ Pbuf, float* __restrict__ Qbuf)
{
  int idx = blockIdx.x * blockDim.x + threadIdx.x;  // over 8*16*2048 = 262144
  if (idx >= BATCH * NSTATE * DINNER) return;
  int d = idx & (DINNER - 1);
  int n = (idx >> 11) & 15;
  int b = idx >> 15;
  float h = 0.f;
  for (int c = 0; c < NCH; c++) {
    size_t o = ((size_t)((b * NCH + c) * NSTATE + n)) * DINNER + d;
    float P = Pbuf[o];
    float q = Qbuf[o];
    Qbuf[o] = h;
    h = P * h + q;
  }
}

// ---------------- chunked scan pass 2: replay with true h_init, emit y ----------------
__global__ __launch_bounds__(64) void scan2_k(
    float* __restrict__ dlt,               // in: delta, out: y (in-place)
    const float* __restrict__ uc,
    const float* __restrict__ dbl, const float* __restrict__ a2t,
    const float* __restrict__ Qbuf)
{
  int c = blockIdx.x;
  int dg = blockIdx.y;
  int b = blockIdx.z;
  int d = dg * 64 + threadIdx.x;
  float a2[NSTATE], h[NSTATE];
  size_t ob = ((size_t)((b * NCH + c) * NSTATE)) * DINNER + d;
  #pragma unroll
  for (int n = 0; n < NSTATE; n++) {
    a2[n] = a2t[n * DINNER + d];
    h[n] = Qbuf[ob + (size_t)n * DINNER];
  }
  size_t base = ((size_t)(b * L_SEQ + c * CH)) * DINNER + d;
  const float* bc = dbl + (size_t)(b * L_SEQ + c * CH) * 96 + 64;
  for (int t = 0; t < CH; t++) {
    float dl = dlt[base];
    float du = dl * uc[base];
    float yv = 0.f;
    #pragma unroll
    for (int n = 0; n < NSTATE; n++) {
      float dA = exp2f(dl * a2[n]);
      h[n] = dA * h[n] + du * bc[n];
      yv += h[n] * bc[NSTATE + n];
    }
    dlt[base] = yv;
    base += DINNER;
    bc += 96;
  }
}

// ---------------- gate: (y + u*D) * silu(r) -> bf16 ----------------
__global__ void gate_k(const float* __restrict__ y, const float* __restrict__ uc,
                       const float* __restrict__ u_r, const float* __restrict__ Dp,
                       unsigned short* __restrict__ y_bf)
{
  int idx = blockIdx.x * blockDim.x + threadIdx.x;  // over 8192*2048
  if (idx >= NROWS * DINNER) return;
  int d = idx & (DINNER - 1);
  int row = idx >> 11;
  float rv = u_r[(size_t)row * (2 * DINNER) + DINNER + d];
  float val = (y[idx] + uc[idx] * Dp[d]) * (rv * sigmoidf_(rv));
  y_bf[idx] = f2bf(val);
}

// ---------------- residual + LN1 -> bf16 ----------------
__global__ __launch_bounds__(256) void ln1_k(
    const float* __restrict__ mamba, const float* __restrict__ item,
    const float* __restrict__ g, const float* __restrict__ bta,
    unsigned short* __restrict__ out_bf)
{
  __shared__ float sbuf[4];
  int i = blockIdx.x;
  int t = threadIdx.x;
  size_t rb = (size_t)i * 1024 + t * 4;
  float4 v = *(const float4*)&mamba[rb];
  float4 w4 = *(const float4*)&item[rb];
  v.x += w4.x; v.y += w4.y; v.z += w4.z; v.w += w4.w;
  float tot = blk_sum(v.x + v.y + v.z + v.w, sbuf);
  float mean = tot * (1.f / 1024.f);
  float dx = v.x - mean, dy = v.y - mean, dz = v.z - mean, dw = v.w - mean;
  float var = blk_sum(dx*dx + dy*dy + dz*dz + dw*dw, sbuf) * (1.f / 1024.f);
  float rstd = rsqrtf(var + 1e-12f);
  float vals[4] = {dx, dy, dz, dw};
  #pragma unroll
  for (int j = 0; j < 4; j++) {
    int c = t * 4 + j;
    out_bf[(size_t)i * 1024 + c] = f2bf(vals[j] * rstd * g[c] + bta[c]);
  }
}

// ---------------- launch ----------------
extern "C" void kernel_launch(void* const* d_in, const int* in_sizes, int n_in,
                              void* d_out, int out_size, void* d_ws, size_t ws_size,
                              hipStream_t stream)
{
  (void)in_sizes; (void)n_in; (void)out_size; (void)ws_size;
  const int*   x     = (const int*)d_in[0];
  const int*   qid   = (const int*)d_in[1];
  const float* emb   = (const float*)d_in[2];
  const float* qc    = (const float*)d_in[3];
  const float* ln0g  = (const float*)d_in[4];
  const float* ln0b  = (const float*)d_in[5];
  const float* w_in  = (const float*)d_in[6];
  const float* convw = (const float*)d_in[7];
  const float* convb = (const float*)d_in[8];
  const float* w_x   = (const float*)d_in[9];
  const float* w_dt  = (const float*)d_in[10];
  const float* dtb   = (const float*)d_in[11];
  const float* Alog  = (const float*)d_in[12];
  const float* Dp    = (const float*)d_in[13];
  const float* w_out = (const float*)d_in[14];
  const float* ln1g  = (const float*)d_in[15];
  const float* ln1b  = (const float*)d_in[16];
  const float* w_fc  = (const float*)d_in[17];
  const float* fcb   = (const float*)d_in[18];
  float* out = (float*)d_out;

  char* base = (char*)d_ws;
  size_t off = 0;
  auto carve = [&](size_t bytes) -> char* {
    char* p = base + off;
    off = (off + bytes + 255) & ~(size_t)255;
    return p;
  };
  float* item  = (float*)carve((size_t)NROWS * 1024 * 4);
  float* u_r   = (float*)carve((size_t)NROWS * 4096 * 4);
  float* uc    = (float*)carve((size_t)NROWS * 2048 * 4);
  float* dbl   = (float*)carve((size_t)NROWS * 96 * 4);
  float* dlt   = (float*)carve((size_t)NROWS * 2048 * 4);
  float* mamba = (float*)carve((size_t)NROWS * 1024 * 4);
  unsigned short* bfbuf  = (unsigned short*)carve((size_t)NROWS * 2048 * 2);
  unsigned short* bw_in  = (unsigned short*)carve((size_t)4096 * 1024 * 2);
  unsigned short* bw_x   = (unsigned short*)carve((size_t)96 * 2048 * 2);
  unsigned short* bw_dt  = (unsigned short*)carve((size_t)2048 * 64 * 2);
  unsigned short* bw_out = (unsigned short*)carve((size_t)1024 * 2048 * 2);
  unsigned short* bw_fc  = (unsigned short*)carve((size_t)4000 * 1024 * 2);
  float* a2t   = (float*)carve((size_t)DINNER * NSTATE * 4);

  // Scan scratch aliases buffers that are dead during the scan window:
  //   Pbuf <- mamba  (written only later by out_proj GEMM)   33.5 MB exact
  //   Qbuf <- bfbuf  (dt_bf consumed by dt_proj GEMM before)  33.5 MB exact
  float* Pbuf = mamba;
  float* Qbuf = (float*)bfbuf;

  auto cv = [&](const float* s, unsigned short* dst, int n) {
    cast_bf16_k<<<(n + 255) / 256, 256, 0, stream>>>(s, dst, n);
  };
  cv(w_in,  bw_in,  4096 * 1024);
  cv(w_x,   bw_x,   96 * 2048);
  cv(w_dt,  bw_dt,  2048 * 64);
  cv(w_out, bw_out, 1024 * 2048);
  cv(w_fc,  bw_fc,  4000 * 1024);
  a2_k<<<(DINNER * NSTATE + 255) / 256, 256, 0, stream>>>(Alog, a2t);

  // 1. embedding gather + concat + LN0
  embed_ln0_k<<<NROWS, 256, 0, stream>>>(x, qid, emb, qc, ln0g, ln0b, item, bfbuf);

  // 2. in_proj: (8192,1024) x (4096,1024)^T -> u_r
  gemm_bt_k<0><<<dim3(64, 32), 256, 0, stream>>>(bfbuf, bw_in, u_r, nullptr, NROWS, 4096, 1024);

  // 3. conv + silu
  conv_silu_k<<<(NROWS * DINNER) / 256, 256, 0, stream>>>(u_r, convw, convb, uc, bfbuf);

  // 4. x_proj: (8192,2048) x (96,2048)^T -> dbl
  gemm_bt_k<0><<<dim3(64, 1), 256, 0, stream>>>(bfbuf, bw_x, dbl, nullptr, NROWS, 96, 2048);

  // 5. dt slice -> bf16
  dt_extract_k<<<(NROWS * DTRANK) / 256, 256, 0, stream>>>(dbl, bfbuf);

  // 6. dt_proj: (8192,64) x (2048,64)^T -> dlt (pre-softplus)
  gemm_bt_k<0><<<dim3(64, 16), 256, 0, stream>>>(bfbuf, bw_dt, dlt, nullptr, NROWS, 2048, 64);

  // 7. softplus(+bias) in place
  softplus_k<<<(NROWS * DINNER) / 256, 256, 0, stream>>>(dlt, dtb);

  // 8. chunked selective scan (delta -> y in place)
  scan1_k<<<dim3(NCH, 32, BATCH), 64, 0, stream>>>(dlt, uc, dbl, a2t, Pbuf, Qbuf);
  scan_carry_k<<<(BATCH * NSTATE * DINNER) / 256, 256, 0, stream>>>(Pbuf, Qbuf);
  scan2_k<<<dim3(NCH, 32, BATCH), 64, 0, stream>>>(dlt, uc, dbl, a2t, Qbuf);

  // 9. gate -> bf16 (overwrites bfbuf; Qbuf dead from here)
  gate_k<<<(NROWS * DINNER) / 256, 256, 0, stream>>>(dlt, uc, u_r, Dp, bfbuf);

  // 10. out_proj: (8192,2048) x (1024,2048)^T -> mamba (overwrites Pbuf; dead)
  gemm_bt_k<0><<<dim3(64, 8), 256, 0, stream>>>(bfbuf, bw_out, mamba, nullptr, NROWS, 1024, 2048);

  // 11. residual + LN1 -> bf16
  ln1_k<<<NROWS, 256, 0, stream>>>(mamba, item, ln1g, ln1b, bfbuf);

  // 12. fc + sigmoid -> out
  gemm_bt_k<1><<<dim3(64, 32), 256, 0, stream>>>(bfbuf, bw_fc, out, fcb, NROWS, 4000, 1024);
}